// Round 9
// baseline (238.064 us; speedup 1.0000x reference)
//
#include <hip/hip_runtime.h>

#define B_   2
#define CIN  16
#define HIN  384
#define WIN  1280
#define CO   24
#define HQ   96
#define WL   320
#define WR   1280
#define DMAX 64

__device__ __forceinline__ float lk(float v) { return v >= 0.f ? v : 0.2f * v; }

// ============ Kernel A: em_left (4x4 s4,4 VALID) + leaky + rc 1x1 + leaky ====
// block 256 = 128 px * 2 o-halves (12 out-ch each); grid 480  [R0 proven body]
__global__ __launch_bounds__(256) void k_left(
    const float* __restrict__ x, const float* __restrict__ w_em,
    const float* __restrict__ b_em, const float* __restrict__ w_rc,
    const float* __restrict__ b_rc, float* __restrict__ out)
{
    __shared__ float smem[CO * CIN * 16];  // em weights during conv, then em acts
    __shared__ float swt[CO * CO];         // rc weights transposed [c][o]
    __shared__ float sbe[CO], sbr[CO];

    for (int i = threadIdx.x; i < CO * CIN * 16; i += 256) smem[i] = w_em[i];
    for (int i = threadIdx.x; i < CO * CO; i += 256) swt[i] = w_rc[(i % CO) * CO + (i / CO)];
    if (threadIdx.x < CO) { sbe[threadIdx.x] = b_em[threadIdx.x]; sbr[threadIdx.x] = b_rc[threadIdx.x]; }
    __syncthreads();

    const int t = threadIdx.x;
    const int half = t >> 7, pxl = t & 127;
    const int obase = half * 12;
    const int flat = blockIdx.x * 128 + pxl;       // < 61440
    const int j = flat % WL, h = (flat / WL) % HQ, b = flat / (WL * HQ);

    float acc[12];
#pragma unroll
    for (int oo = 0; oo < 12; ++oo) acc[oo] = sbe[obase + oo];

    for (int c = 0; c < CIN; ++c) {
#pragma unroll
        for (int kh = 0; kh < 4; ++kh) {
            const float4 v = *(const float4*)(x + ((size_t)(b * CIN + c) * HIN + 4 * h + kh) * WIN + 4 * j);
#pragma unroll
            for (int oo = 0; oo < 12; ++oo) {
                const float4 wv = *(const float4*)&smem[(((obase + oo) * CIN + c) * 4 + kh) * 4];
                acc[oo] += v.x * wv.x + v.y * wv.y + v.z * wv.z + v.w * wv.w;
            }
        }
    }
    __syncthreads();
#pragma unroll
    for (int oo = 0; oo < 12; ++oo) smem[(obase + oo) * 128 + pxl] = lk(acc[oo]);
    __syncthreads();

    float acc2[12];
#pragma unroll
    for (int oo = 0; oo < 12; ++oo) acc2[oo] = sbr[obase + oo];
    for (int c = 0; c < CO; ++c) {
        const float in_c = smem[c * 128 + pxl];
#pragma unroll
        for (int oo = 0; oo < 12; ++oo) acc2[oo] += in_c * swt[c * CO + obase + oo];
    }
#pragma unroll
    for (int oo = 0; oo < 12; ++oo)
        out[((size_t)(b * CO + obase + oo) * HQ + h) * WL + j] = lk(acc2[oo]);
}

// ======= Kernel B: em_right (4x4 s4,1 pad 1,2) + leaky + rc 1x1 + leaky ======
// R5 version EXACT (71us, VGPR 60, occ 32%): single row, 4 px/thread, LDS
// union 27136B, fmaf chains, float4 swt reads. Fusion with k_left is
// FALSIFIED twice (R2 +54us, R8 +21us): heterogeneous blocks interleave
// badly (occ 26.6 vs 32.5) + dual-body instruction footprint. Keep separate.
__global__ __launch_bounds__(256) void k_right(
    const float* __restrict__ x, const float* __restrict__ w_em,
    const float* __restrict__ b_em, const float* __restrict__ w_rc,
    const float* __restrict__ b_rc, float* __restrict__ out)
{
    __shared__ __align__(16) float sw[CO * CIN * 16];  // weights, then em acts [24][256]
    __shared__ __align__(16) float swt[CO * CO];
    __shared__ float sbe[CO], sbr[CO];

    for (int i = threadIdx.x; i < CO * CIN * 16; i += 256) sw[i] = w_em[i];
    for (int i = threadIdx.x; i < CO * CO; i += 256) swt[i] = w_rc[(i % CO) * CO + (i / CO)];
    if (threadIdx.x < CO) { sbe[threadIdx.x] = b_em[threadIdx.x]; sbr[threadIdx.x] = b_rc[threadIdx.x]; }
    __syncthreads();

    const int t = threadIdx.x;
    const int L = t & 63, quarter = t >> 6;
    const int obase = quarter * 6;
    const int row = blockIdx.x / 5, jbase = (blockIdx.x % 5) * 256;
    const int b = row / HQ, h = row % HQ;

    const bool vm1 = (jbase + 4 * L) > 0;
    const bool vp  = (jbase + 4 * L + 4) < WIN;
    const int  om1 = vm1 ? (4 * L - 2) : 0;
    const int  op4 = vp  ? (4 * L + 4) : 0;

    float acc[4][6];
#pragma unroll
    for (int k = 0; k < 4; ++k)
#pragma unroll
        for (int oo = 0; oo < 6; ++oo) acc[k][oo] = sbe[obase + oo];

    for (int c = 0; c < CIN; ++c) {
#pragma unroll
        for (int kh = 0; kh < 4; ++kh) {
            const float* xr = x + ((size_t)(b * CIN + c) * HIN + 4 * h + kh) * WIN + jbase;
            const float4  v = *(const float4*)(xr + 4 * L);
            const float2  A = *(const float2*)(xr + om1);   // cols 4L-2, 4L-1
            const float2  C = *(const float2*)(xr + op4);   // cols 4L+4, 4L+5
            float in[7];
            in[0] = vm1 ? A.y : 0.f;
            in[1] = v.x; in[2] = v.y; in[3] = v.z; in[4] = v.w;
            in[5] = vp ? C.x : 0.f;
            in[6] = vp ? C.y : 0.f;
#pragma unroll
            for (int oo = 0; oo < 6; ++oo) {
                const float4 wv = *(const float4*)&sw[(((obase + oo) * CIN + c) * 4 + kh) * 4];
#pragma unroll
                for (int k = 0; k < 4; ++k) {
                    float a = acc[k][oo];
                    a = fmaf(in[k],     wv.x, a);
                    a = fmaf(in[k + 1], wv.y, a);
                    a = fmaf(in[k + 2], wv.z, a);
                    a = fmaf(in[k + 3], wv.w, a);
                    acc[k][oo] = a;
                }
            }
        }
    }
    __syncthreads();   // all waves done reading em weights; sw becomes act buffer
#pragma unroll
    for (int oo = 0; oo < 6; ++oo) {
        float4 st = make_float4(lk(acc[0][oo]), lk(acc[1][oo]), lk(acc[2][oo]), lk(acc[3][oo]));
        *(float4*)&sw[(obase + oo) * 256 + 4 * L] = st;
    }
    __syncthreads();

    float acc2[CO];
#pragma unroll
    for (int o = 0; o < CO; ++o) acc2[o] = sbr[o];
    for (int c = 0; c < CO; ++c) {
        const float in_c = sw[c * 256 + t];
#pragma unroll
        for (int m = 0; m < 6; ++m) {
            const float4 wv = *(const float4*)&swt[c * CO + 4 * m];   // 16B aligned
            acc2[4 * m + 0] = fmaf(in_c, wv.x, acc2[4 * m + 0]);
            acc2[4 * m + 1] = fmaf(in_c, wv.y, acc2[4 * m + 1]);
            acc2[4 * m + 2] = fmaf(in_c, wv.z, acc2[4 * m + 2]);
            acc2[4 * m + 3] = fmaf(in_c, wv.w, acc2[4 * m + 3]);
        }
    }
#pragma unroll
    for (int o = 0; o < CO; ++o)
        out[((size_t)(b * CO + o) * HQ + h) * WR + jbase + t] = lk(acc2[o]);
}

// ====== Kernel C: cost volume + min/argmin + tf 1x1 + output assembly ========
// R8 hybrid EXACT (confirmed ~-22us): R6's conflict-free gather (lane stride
// 16B contiguous) + R7's parallel tail (tf 1x1 split across all 4 waves;
// g-reduction same-address across waves -> LDS broadcast, free).
// block 256 = 64 j-lanes x 4 waves (wave w owns d in [16w,16w+16)); grid 960.
// Channel-ascending += of fabsf keeps costs bitwise-identical.
__global__ __launch_bounds__(256) void k_cost(
    const float* __restrict__ fl, const float* __restrict__ fr,
    const float* __restrict__ wtf, const float* __restrict__ btf,
    float* __restrict__ out, float* __restrict__ cost)
{
    __shared__ float frs[CO * 324];       // 31104 B
    __shared__ float sbest[256];
    __shared__ int   sbd[256];

    const int t  = threadIdx.x;
    const int j  = t & 63;                 // lane = local col
    const int w  = t >> 6;                 // wave: d in [16w, 16w+16)
    const int jc = blockIdx.x % 5;
    const int r  = blockIdx.x / 5;
    const int h  = r % HQ, b = r / HQ;
    const int j0 = jc * 64;
    const int jg = j0 + j;
    const int colbase = 4 * j0 - 64;

    // stage 24 rows x 320 cols (coalesced; left-clip replication)
    for (int idx = t; idx < CO * 320; idx += 256) {
        const int c = idx / 320, Wd = idx % 320;
        const int col = colbase + Wd;
        frs[c * 324 + 2 + Wd] = fr[((size_t)(b * CO + c) * HQ + h) * WR + (col > 0 ? col : 0)];
    }
    __syncthreads();

    float acc[4][4];                       // [q][r], d = 16w + 4q + r
#pragma unroll
    for (int q = 0; q < 4; ++q)
#pragma unroll
        for (int rr = 0; rr < 4; ++rr) acc[q][rr] = 0.f;

    for (int c = 0; c < CO; ++c) {
        const float flc = fl[((size_t)(b * CO + c) * HQ + h) * WL + jg];
        const float* base = &frs[c * 324 + 4 * j + 64];
#pragma unroll
        for (int q = 0; q < 4; ++q) {
            const int D = 4 * w + q;
            const float4 v = *(const float4*)(base - 4 * D);  // 16B-aligned, lanes contiguous
            acc[q][0] += fabsf(flc - v.w);   // d = 4D
            acc[q][1] += fabsf(flc - v.z);   // d = 4D+1
            acc[q][2] += fabsf(flc - v.y);   // d = 4D+2
            acc[q][3] += fabsf(flc - v.x);   // d = 4D+3
        }
    }

    // cost volume writes (coalesced over jg)
#pragma unroll
    for (int q = 0; q < 4; ++q)
#pragma unroll
        for (int rr = 0; rr < 4; ++rr) {
            const int d = 16 * w + 4 * q + rr;
            cost[((size_t)(b * DMAX + d) * HQ + h) * WL + jg] = acc[q][rr];
        }

    // per-thread min / first-occurrence argmin (ascending d within wave range)
    float best = acc[0][0]; int bd = 16 * w;
#pragma unroll
    for (int q = 0; q < 4; ++q)
#pragma unroll
        for (int rr = 0; rr < 4; ++rr) {
            if (q == 0 && rr == 0) continue;
            const int d = 16 * w + 4 * q + rr;
            if (acc[q][rr] < best) { best = acc[q][rr]; bd = d; }
        }
    sbest[t] = best; sbd[t] = bd;
    __syncthreads();

    // all 4 waves: g-ascending reduce (same addrs across waves -> broadcast),
    // then each wave computes its share of the 13 tf outputs.
    float cur = sbest[j]; int curd = sbd[j];
#pragma unroll
    for (int g = 1; g < 4; ++g) {
        const float v = sbest[g * 64 + j];
        if (v < cur) { cur = v; curd = sbd[g * 64 + j]; }
    }
    float flr[CO];
#pragma unroll
    for (int c = 0; c < CO; ++c) flr[c] = fl[((size_t)(b * CO + c) * HQ + h) * WL + jg];

    const int o_lo = (w == 0) ? 0 : 4 * w - 3;   // 0,1,5,9
    const int o_hi = 4 * w + 1;                   // 1,5,9,13
    for (int o = o_lo; o < o_hi; ++o) {
        float a = btf[o] + wtf[o * 25] * cur;
#pragma unroll
        for (int c = 0; c < CO; ++c) a += wtf[o * 25 + 1 + c] * flr[c];
        out[((size_t)(b * 16 + 3 + o) * HQ + h) * WL + jg] = lk(a);
    }
    if (w == 0) {
        out[((size_t)(b * 16 + 0) * HQ + h) * WL + jg] = (float)curd;
        out[((size_t)(b * 16 + 1) * HQ + h) * WL + jg] = 0.f;
        out[((size_t)(b * 16 + 2) * HQ + h) * WL + jg] = 0.f;
    }
}

extern "C" void kernel_launch(void* const* d_in, const int* in_sizes, int n_in,
                              void* d_out, int out_size, void* d_ws, size_t ws_size,
                              hipStream_t stream) {
    const float* fl_in = (const float*)d_in[0];
    const float* fr_in = (const float*)d_in[1];
    // d_in[2] = max_disp (int) -- fixed 64
    const float* w_em = (const float*)d_in[3];
    const float* b_em = (const float*)d_in[4];
    const float* w_rc = (const float*)d_in[5];
    const float* b_rc = (const float*)d_in[6];
    const float* w_tf = (const float*)d_in[7];
    const float* b_tf = (const float*)d_in[8];

    float* out  = (float*)d_out;
    float* cost = out + (size_t)B_ * 16 * HQ * WL;

    float* fl_ws = (float*)d_ws;                               // [2,24,96,320]
    float* fr_ws = fl_ws + (size_t)B_ * CO * HQ * WL;          // [2,24,96,1280]

    hipLaunchKernelGGL(k_right, dim3(960), dim3(256), 0, stream,
                       fr_in, w_em, b_em, w_rc, b_rc, fr_ws);
    hipLaunchKernelGGL(k_left,  dim3(480), dim3(256), 0, stream,
                       fl_in, w_em, b_em, w_rc, b_rc, fl_ws);
    hipLaunchKernelGGL(k_cost,  dim3(960), dim3(256), 0, stream,
                       fl_ws, fr_ws, w_tf, b_tf, out, cost);
}

// Round 10
// 231.293 us; speedup vs baseline: 1.0293x; 1.0293x over previous
//
#include <hip/hip_runtime.h>

#define B_   2
#define CIN  16
#define HIN  384
#define WIN  1280
#define CO   24
#define HQ   96
#define WL   320
#define WR   1280
#define DMAX 64

__device__ __forceinline__ float lk(float v) { return v >= 0.f ? v : 0.2f * v; }

// ============ Fused embedding kernel: right (blocks 0..959) + left (960..1439)
// R10: TAIL-APPEND fusion. R8/R9 established per-launch gap g ~= 21us
// (R8 fused broke even: +20us kernel vs -21us launch). R8's %3 interleave
// mixed short/long blocks on every CU (occ 26.6 vs 32.5 pure). Tail-append
// keeps the right phase homogeneous (in-order dispatch); left blocks backfill
// as right drains -- two launches' schedule, one launch's overhead.
// Bodies are EXACT copies of the proven R5 right / R0 left kernels.
// LDS identical shape for both branches: 27136 B. WATCH: VGPR<=96, occ ~32%.
__global__ __launch_bounds__(256) void k_em(
    const float* __restrict__ xl, const float* __restrict__ xr,
    const float* __restrict__ w_em, const float* __restrict__ b_em,
    const float* __restrict__ w_rc, const float* __restrict__ b_rc,
    float* __restrict__ out_l, float* __restrict__ out_r)
{
    __shared__ __align__(16) float buf[CO * CIN * 16];  // weights, then acts
    __shared__ __align__(16) float swt[CO * CO];        // rc weights [c][o]
    __shared__ float sbe[CO], sbr[CO];

    for (int i = threadIdx.x; i < CO * CIN * 16; i += 256) buf[i] = w_em[i];
    for (int i = threadIdx.x; i < CO * CO; i += 256) swt[i] = w_rc[(i % CO) * CO + (i / CO)];
    if (threadIdx.x < CO) { sbe[threadIdx.x] = b_em[threadIdx.x]; sbr[threadIdx.x] = b_rc[threadIdx.x]; }
    __syncthreads();

    const int t = threadIdx.x;

    if (blockIdx.x < 960) {
        // ---------------- RIGHT branch (4x4 s4,1 pad 1,2) -- exact R5 body ---
        const int rb = blockIdx.x;
        const int L = t & 63, quarter = t >> 6;
        const int obase = quarter * 6;
        const int row = rb / 5, jbase = (rb % 5) * 256;
        const int b = row / HQ, h = row % HQ;

        const bool vm1 = (jbase + 4 * L) > 0;
        const bool vp  = (jbase + 4 * L + 4) < WIN;
        const int  om1 = vm1 ? (4 * L - 2) : 0;
        const int  op4 = vp  ? (4 * L + 4) : 0;

        float acc[4][6];
#pragma unroll
        for (int k = 0; k < 4; ++k)
#pragma unroll
            for (int oo = 0; oo < 6; ++oo) acc[k][oo] = sbe[obase + oo];

        for (int c = 0; c < CIN; ++c) {
#pragma unroll
            for (int kh = 0; kh < 4; ++kh) {
                const float* xp = xr + ((size_t)(b * CIN + c) * HIN + 4 * h + kh) * WIN + jbase;
                const float4  v = *(const float4*)(xp + 4 * L);
                const float2  A = *(const float2*)(xp + om1);   // cols 4L-2, 4L-1
                const float2  C = *(const float2*)(xp + op4);   // cols 4L+4, 4L+5
                float in[7];
                in[0] = vm1 ? A.y : 0.f;
                in[1] = v.x; in[2] = v.y; in[3] = v.z; in[4] = v.w;
                in[5] = vp ? C.x : 0.f;
                in[6] = vp ? C.y : 0.f;
#pragma unroll
                for (int oo = 0; oo < 6; ++oo) {
                    const float4 wv = *(const float4*)&buf[(((obase + oo) * CIN + c) * 4 + kh) * 4];
#pragma unroll
                    for (int k = 0; k < 4; ++k) {
                        float a = acc[k][oo];
                        a = fmaf(in[k],     wv.x, a);
                        a = fmaf(in[k + 1], wv.y, a);
                        a = fmaf(in[k + 2], wv.z, a);
                        a = fmaf(in[k + 3], wv.w, a);
                        acc[k][oo] = a;
                    }
                }
            }
        }
        __syncthreads();   // done reading em weights; buf becomes act buffer [24][256]
#pragma unroll
        for (int oo = 0; oo < 6; ++oo) {
            float4 st = make_float4(lk(acc[0][oo]), lk(acc[1][oo]), lk(acc[2][oo]), lk(acc[3][oo]));
            *(float4*)&buf[(obase + oo) * 256 + 4 * L] = st;
        }
        __syncthreads();

        float acc2[CO];
#pragma unroll
        for (int o = 0; o < CO; ++o) acc2[o] = sbr[o];
        for (int c = 0; c < CO; ++c) {
            const float in_c = buf[c * 256 + t];
#pragma unroll
            for (int m = 0; m < 6; ++m) {
                const float4 wv = *(const float4*)&swt[c * CO + 4 * m];   // 16B aligned
                acc2[4 * m + 0] = fmaf(in_c, wv.x, acc2[4 * m + 0]);
                acc2[4 * m + 1] = fmaf(in_c, wv.y, acc2[4 * m + 1]);
                acc2[4 * m + 2] = fmaf(in_c, wv.z, acc2[4 * m + 2]);
                acc2[4 * m + 3] = fmaf(in_c, wv.w, acc2[4 * m + 3]);
            }
        }
#pragma unroll
        for (int o = 0; o < CO; ++o)
            out_r[((size_t)(b * CO + o) * HQ + h) * WR + jbase + t] = lk(acc2[o]);
    } else {
        // ---------------- LEFT branch (4x4 s4,4 VALID) -- exact R0 body ------
        const int lb = blockIdx.x - 960;
        const int half = t >> 7, pxl = t & 127;
        const int obase = half * 12;
        const int flat = lb * 128 + pxl;              // < 61440
        const int j = flat % WL, h = (flat / WL) % HQ, b = flat / (WL * HQ);

        float acc[12];
#pragma unroll
        for (int oo = 0; oo < 12; ++oo) acc[oo] = sbe[obase + oo];

        for (int c = 0; c < CIN; ++c) {
#pragma unroll
            for (int kh = 0; kh < 4; ++kh) {
                const float4 v = *(const float4*)(xl + ((size_t)(b * CIN + c) * HIN + 4 * h + kh) * WIN + 4 * j);
#pragma unroll
                for (int oo = 0; oo < 12; ++oo) {
                    const float4 wv = *(const float4*)&buf[(((obase + oo) * CIN + c) * 4 + kh) * 4];
                    acc[oo] += v.x * wv.x + v.y * wv.y + v.z * wv.z + v.w * wv.w;
                }
            }
        }
        __syncthreads();
#pragma unroll
        for (int oo = 0; oo < 12; ++oo) buf[(obase + oo) * 128 + pxl] = lk(acc[oo]);
        __syncthreads();

        float acc2[12];
#pragma unroll
        for (int oo = 0; oo < 12; ++oo) acc2[oo] = sbr[obase + oo];
        for (int c = 0; c < CO; ++c) {
            const float in_c = buf[c * 128 + pxl];
#pragma unroll
            for (int oo = 0; oo < 12; ++oo) acc2[oo] += in_c * swt[c * CO + obase + oo];
        }
#pragma unroll
        for (int oo = 0; oo < 12; ++oo)
            out_l[((size_t)(b * CO + obase + oo) * HQ + h) * WL + j] = lk(acc2[oo]);
    }
}

// ====== Kernel C: cost volume + min/argmin + tf 1x1 + output assembly ========
// R8 hybrid EXACT: R6's conflict-free gather (lane stride 16B contiguous) +
// R7's parallel tail (tf 1x1 split across all 4 waves; g-reduction
// same-address across waves -> LDS broadcast, free).
// block 256 = 64 j-lanes x 4 waves (wave w owns d in [16w,16w+16)); grid 960.
// Channel-ascending += of fabsf keeps costs bitwise-identical.
__global__ __launch_bounds__(256) void k_cost(
    const float* __restrict__ fl, const float* __restrict__ fr,
    const float* __restrict__ wtf, const float* __restrict__ btf,
    float* __restrict__ out, float* __restrict__ cost)
{
    __shared__ float frs[CO * 324];       // 31104 B
    __shared__ float sbest[256];
    __shared__ int   sbd[256];

    const int t  = threadIdx.x;
    const int j  = t & 63;                 // lane = local col
    const int w  = t >> 6;                 // wave: d in [16w, 16w+16)
    const int jc = blockIdx.x % 5;
    const int r  = blockIdx.x / 5;
    const int h  = r % HQ, b = r / HQ;
    const int j0 = jc * 64;
    const int jg = j0 + j;
    const int colbase = 4 * j0 - 64;

    // stage 24 rows x 320 cols (coalesced; left-clip replication)
    for (int idx = t; idx < CO * 320; idx += 256) {
        const int c = idx / 320, Wd = idx % 320;
        const int col = colbase + Wd;
        frs[c * 324 + 2 + Wd] = fr[((size_t)(b * CO + c) * HQ + h) * WR + (col > 0 ? col : 0)];
    }
    __syncthreads();

    float acc[4][4];                       // [q][r], d = 16w + 4q + r
#pragma unroll
    for (int q = 0; q < 4; ++q)
#pragma unroll
        for (int rr = 0; rr < 4; ++rr) acc[q][rr] = 0.f;

    for (int c = 0; c < CO; ++c) {
        const float flc = fl[((size_t)(b * CO + c) * HQ + h) * WL + jg];
        const float* base = &frs[c * 324 + 4 * j + 64];
#pragma unroll
        for (int q = 0; q < 4; ++q) {
            const int D = 4 * w + q;
            const float4 v = *(const float4*)(base - 4 * D);  // 16B-aligned, lanes contiguous
            acc[q][0] += fabsf(flc - v.w);   // d = 4D
            acc[q][1] += fabsf(flc - v.z);   // d = 4D+1
            acc[q][2] += fabsf(flc - v.y);   // d = 4D+2
            acc[q][3] += fabsf(flc - v.x);   // d = 4D+3
        }
    }

    // cost volume writes (coalesced over jg)
#pragma unroll
    for (int q = 0; q < 4; ++q)
#pragma unroll
        for (int rr = 0; rr < 4; ++rr) {
            const int d = 16 * w + 4 * q + rr;
            cost[((size_t)(b * DMAX + d) * HQ + h) * WL + jg] = acc[q][rr];
        }

    // per-thread min / first-occurrence argmin (ascending d within wave range)
    float best = acc[0][0]; int bd = 16 * w;
#pragma unroll
    for (int q = 0; q < 4; ++q)
#pragma unroll
        for (int rr = 0; rr < 4; ++rr) {
            if (q == 0 && rr == 0) continue;
            const int d = 16 * w + 4 * q + rr;
            if (acc[q][rr] < best) { best = acc[q][rr]; bd = d; }
        }
    sbest[t] = best; sbd[t] = bd;
    __syncthreads();

    // all 4 waves: g-ascending reduce (same addrs across waves -> broadcast),
    // then each wave computes its share of the 13 tf outputs.
    float cur = sbest[j]; int curd = sbd[j];
#pragma unroll
    for (int g = 1; g < 4; ++g) {
        const float v = sbest[g * 64 + j];
        if (v < cur) { cur = v; curd = sbd[g * 64 + j]; }
    }
    float flr[CO];
#pragma unroll
    for (int c = 0; c < CO; ++c) flr[c] = fl[((size_t)(b * CO + c) * HQ + h) * WL + jg];

    const int o_lo = (w == 0) ? 0 : 4 * w - 3;   // 0,1,5,9
    const int o_hi = 4 * w + 1;                   // 1,5,9,13
    for (int o = o_lo; o < o_hi; ++o) {
        float a = btf[o] + wtf[o * 25] * cur;
#pragma unroll
        for (int c = 0; c < CO; ++c) a += wtf[o * 25 + 1 + c] * flr[c];
        out[((size_t)(b * 16 + 3 + o) * HQ + h) * WL + jg] = lk(a);
    }
    if (w == 0) {
        out[((size_t)(b * 16 + 0) * HQ + h) * WL + jg] = (float)curd;
        out[((size_t)(b * 16 + 1) * HQ + h) * WL + jg] = 0.f;
        out[((size_t)(b * 16 + 2) * HQ + h) * WL + jg] = 0.f;
    }
}

extern "C" void kernel_launch(void* const* d_in, const int* in_sizes, int n_in,
                              void* d_out, int out_size, void* d_ws, size_t ws_size,
                              hipStream_t stream) {
    const float* fl_in = (const float*)d_in[0];
    const float* fr_in = (const float*)d_in[1];
    // d_in[2] = max_disp (int) -- fixed 64
    const float* w_em = (const float*)d_in[3];
    const float* b_em = (const float*)d_in[4];
    const float* w_rc = (const float*)d_in[5];
    const float* b_rc = (const float*)d_in[6];
    const float* w_tf = (const float*)d_in[7];
    const float* b_tf = (const float*)d_in[8];

    float* out  = (float*)d_out;
    float* cost = out + (size_t)B_ * 16 * HQ * WL;

    float* fl_ws = (float*)d_ws;                               // [2,24,96,320]
    float* fr_ws = fl_ws + (size_t)B_ * CO * HQ * WL;          // [2,24,96,1280]

    hipLaunchKernelGGL(k_em, dim3(1440), dim3(256), 0, stream,
                       fl_in, fr_in, w_em, b_em, w_rc, b_rc, fl_ws, fr_ws);
    hipLaunchKernelGGL(k_cost, dim3(960), dim3(256), 0, stream,
                       fl_ws, fr_ws, w_tf, b_tf, out, cost);
}